// Round 17
// baseline (11885.259 us; speedup 1.0000x reference)
//
#include <hip/hip_runtime.h>

// MultiTaskLSTM: B=512, T=1024, I=64, H=256
// R17 = R16 with the global_load_lds source address FIXED to be per-lane
// (gp + lane*16): the LDS dest is wave-uniform base + lane*16, but the
// global src must carry the lane offset explicitly (guide §5 caveat, m104).
// R16's absmax=0.245 was 64 copies of word 0 per slot. Structure unchanged:
// zero-exchange, 32 blocks x 16 rows, tiles 0,1 in registers, tiles 2..7
// streamed as 12 half-tile chunks through 3 rotating LDS slots with counted
// vmcnt(10); h single-buffered in LDS with raw s_barriers (no vm drain).

typedef __attribute__((ext_vector_type(4))) float f32x4;
typedef __attribute__((ext_vector_type(4))) unsigned int u32x4;
typedef __attribute__((ext_vector_type(8))) short bf16x8;
typedef __attribute__((ext_vector_type(8))) unsigned short u16x8;

#define T_SZ 1024
#define I_SZ 64
#define H_SZ 256
#define KFRAGS 10
#define NTHREADS 512
#define NBLK 32

#define WT_FRAGS (64 * KFRAGS * 64)
#define WS_BIAS_OFF (WT_FRAGS * 16)

#define HST 264                             // h_lds row stride (u16)

__device__ __forceinline__ unsigned short f2bf(float f) {
    unsigned int u = __builtin_bit_cast(unsigned int, f);
    unsigned int r = (u + 0x7FFFu + ((u >> 16) & 1u)) >> 16;
    return (unsigned short)r;
}
__device__ __forceinline__ float bf2f(unsigned short s) {
    unsigned int u = ((unsigned int)s) << 16;
    return __builtin_bit_cast(float, u);
}
__device__ __forceinline__ float sigm(float x) {
    return 1.0f / (1.0f + exp2f(-1.44269504f * x));
}
__device__ __forceinline__ float tanhfast(float x) {
    float e = exp2f(2.88539008f * x);
    return 1.0f - 2.0f / (e + 1.0f);
}

__device__ __forceinline__ void gload_lds(const void* g, void* l) {
    __builtin_amdgcn_global_load_lds(
        (const __attribute__((address_space(1))) void*)g,
        (__attribute__((address_space(3))) void*)l, 16, 0, 0);
}

// W pack (identical to R15/R16): frag id = ((w*8 + t)*10 + kf); n = lane&15:
//   gate = t&3, cg = t>>2; gate row g = gate*256 + w*32 + cg*16 + n
//   k = kf*32 + (lane>>4)*8 + j  (k<256 -> W_hh, else W_ih)
__global__ void prep_kernel(const float* __restrict__ W_ih,
                            const float* __restrict__ W_hh,
                            const float* __restrict__ b_ih,
                            const float* __restrict__ b_hh,
                            unsigned short* __restrict__ Wt,
                            float* __restrict__ bias) {
    int gid = blockIdx.x * blockDim.x + threadIdx.x;
    if (gid < WT_FRAGS) {
        int lane = gid & 63;
        int rest = gid >> 6;
        int kf = rest % KFRAGS;
        int tileid = rest / KFRAGS;
        int w  = tileid >> 3;
        int tt = tileid & 7;
        int g = (tt & 3) * 256 + w * 32 + (tt >> 2) * 16 + (lane & 15);
        int k0 = kf * 32 + (lane >> 4) * 8;
        u16x8 v;
        #pragma unroll
        for (int j = 0; j < 8; ++j) {
            int k = k0 + j;
            float wv = (k < H_SZ) ? W_hh[g * H_SZ + k]
                                  : W_ih[g * I_SZ + (k - H_SZ)];
            v[j] = f2bf(wv);
        }
        ((u16x8*)Wt)[gid] = v;
    } else if (gid < WT_FRAGS + 1024) {
        int j = gid - WT_FRAGS;
        bias[j] = b_ih[j] + b_hh[j];
    }
}

#define MFMA16(A, B, C) __builtin_amdgcn_mfma_f32_16x16x32_bf16(A, B, C, 0, 0, 0)

#define TILE10(ACC, B) do { \
    ACC = MFMA16(ah[0], B[0], ACC); \
    ACC = MFMA16(ah[1], B[1], ACC); \
    ACC = MFMA16(ah[2], B[2], ACC); \
    ACC = MFMA16(ah[3], B[3], ACC); \
    ACC = MFMA16(ah[4], B[4], ACC); \
    ACC = MFMA16(ah[5], B[5], ACC); \
    ACC = MFMA16(ah[6], B[6], ACC); \
    ACC = MFMA16(ah[7], B[7], ACC); \
    ACC = MFMA16(xf0,   B[8], ACC); \
    ACC = MFMA16(xf1,   B[9], ACC); } while (0)

// issue chunk C (tile 2+(C>>1), half C&1) into slot C%3.
// PER-LANE global src (base + lane*16); wave-uniform LDS dest (+ lane*16 HW).
#define ISSUE(C) do { \
    const char* gp_ = (const char*)Wt + (size_t)lane * 16 + \
        (size_t)((wave * 8 + 2 + ((C) >> 1)) * KFRAGS + ((C) & 1) * 5) * 1024; \
    unsigned short* lp_ = &wsl[wave][(C) % 3][0]; \
    gload_lds(gp_ + 0 * 1024, lp_ + 0 * 512); \
    gload_lds(gp_ + 1 * 1024, lp_ + 1 * 512); \
    gload_lds(gp_ + 2 * 1024, lp_ + 2 * 512); \
    gload_lds(gp_ + 3 * 1024, lp_ + 3 * 512); \
    gload_lds(gp_ + 4 * 1024, lp_ + 4 * 512); \
} while (0)

// consume chunk: counted vmcnt -> LDS reads -> lgkm drain -> reissue -> MFMAs
#define CHUNK(VMN, SLOT, ACC, HALF, DOISSUE) do { \
    asm volatile("s_waitcnt vmcnt(" VMN ")" ::: "memory"); \
    __builtin_amdgcn_sched_barrier(0); \
    const unsigned short* sp_ = &wsl[wave][SLOT][0]; \
    bf16x8 q0 = *(const bf16x8*)(sp_ + 0 * 512 + lane * 8); \
    bf16x8 q1 = *(const bf16x8*)(sp_ + 1 * 512 + lane * 8); \
    bf16x8 q2 = *(const bf16x8*)(sp_ + 2 * 512 + lane * 8); \
    bf16x8 q3 = *(const bf16x8*)(sp_ + 3 * 512 + lane * 8); \
    bf16x8 q4 = *(const bf16x8*)(sp_ + 4 * 512 + lane * 8); \
    asm volatile("s_waitcnt lgkmcnt(0)" ::: "memory"); \
    __builtin_amdgcn_sched_barrier(0); \
    DOISSUE; \
    if ((HALF) == 0) { \
        ACC = MFMA16(ah[0], q0, ACC); \
        ACC = MFMA16(ah[1], q1, ACC); \
        ACC = MFMA16(ah[2], q2, ACC); \
        ACC = MFMA16(ah[3], q3, ACC); \
        ACC = MFMA16(ah[4], q4, ACC); \
    } else { \
        ACC = MFMA16(ah[5], q0, ACC); \
        ACC = MFMA16(ah[6], q1, ACC); \
        ACC = MFMA16(ah[7], q2, ACC); \
        ACC = MFMA16(xf0,   q3, ACC); \
        ACC = MFMA16(xf1,   q4, ACC); \
    } \
} while (0)

// elementwise for one colgrp: gates fully in-register; write h to h_lds
#define EW(AI, AF, AG, AO, C, BI, BF, BG, BO, CG) do { \
    _Pragma("unroll") \
    for (int q_ = 0; q_ < 4; ++q_) { \
        float gi = AI[q_] + BI, gf = AF[q_] + BF; \
        float gg_ = AG[q_] + BG, go = AO[q_] + BO; \
        float ii = sigm(gi), ff = sigm(gf); \
        float gv = tanhfast(gg_), oo = sigm(go); \
        float cc_ = ff * C[q_] + ii * gv; C[q_] = cc_; \
        float hh = oo * tanhfast(cc_); \
        unsigned hu = (unsigned)f2bf(hh); \
        unsigned pr = (unsigned)__shfl_xor((int)hu, 1); \
        if (!(lane & 1)) { \
            *(unsigned*)&h_lds[(rb + q_) * HST + wave * 32 + (CG) * 16 + n] = \
                hu | (pr << 16); \
        } \
    } } while (0)

__global__ __launch_bounds__(NTHREADS, 2)
void lstm_kernel(const float* __restrict__ x,
                 const unsigned short* __restrict__ Wt,
                 const float* __restrict__ bias,
                 const float* __restrict__ W_dir, const float* __restrict__ b_dir,
                 const float* __restrict__ W_q,   const float* __restrict__ b_q,
                 const float* __restrict__ W_rr,  const float* __restrict__ b_rr,
                 const float* __restrict__ W_sl,  const float* __restrict__ b_sl,
                 float* __restrict__ out)
{
    __shared__ __align__(16) unsigned short h_lds[16 * HST];       // 8448 B
    __shared__ __align__(16) unsigned short wsl[8][3][5 * 512];    // 122880 B

    const int tid  = threadIdx.x;
    const int lane = tid & 63;
    const int wave = tid >> 6;
    const int b0   = blockIdx.x * 16;
    const int n    = lane & 15;
    const int hg   = lane >> 4;
    const int rb   = hg * 4;

    // ---- register-resident W: tiles 0,1 ----
    bf16x8 wr0[KFRAGS], wr1[KFRAGS];
    #pragma unroll
    for (int kf = 0; kf < KFRAGS; ++kf) {
        wr0[kf] = *(const bf16x8*)(Wt +
            ((size_t)((wave * 8 + 0) * KFRAGS + kf) * 64 + lane) * 8);
        wr1[kf] = *(const bf16x8*)(Wt +
            ((size_t)((wave * 8 + 1) * KFRAGS + kf) * 64 + lane) * 8);
    }

    const int col0 = wave * 32 + n;
    const int col1 = wave * 32 + 16 + n;
    const float bI0 = bias[col0],       bF0 = bias[256 + col0];
    const float bG0 = bias[512 + col0], bO0 = bias[768 + col0];
    const float bI1 = bias[col1],       bF1 = bias[256 + col1];
    const float bG1 = bias[512 + col1], bO1 = bias[768 + col1];

    // ---- zero h (h_0 = 0) ----
    {
        unsigned int* hz = (unsigned int*)&h_lds[0];
        for (int i = tid; i < (16 * HST) / 2; i += NTHREADS) hz[i] = 0u;
    }

    float c0[4] = {0.f, 0.f, 0.f, 0.f};
    float c1[4] = {0.f, 0.f, 0.f, 0.f};

    // ---- x_0 ----
    const float* xbase = x + (size_t)(b0 + n) * (T_SZ * I_SZ) + hg * 8;
    f32x4 xa, xb, xc, xd;
    bf16x8 xf0, xf1;
    {
        xa = *(const f32x4*)xbase;
        xb = *(const f32x4*)(xbase + 4);
        xc = *(const f32x4*)(xbase + 32);
        xd = *(const f32x4*)(xbase + 36);
        unsigned p0, p1, p2, p3, p4, p5, p6, p7;
        asm("v_cvt_pk_bf16_f32 %0, %1, %2" : "=v"(p0) : "v"(xa[0]), "v"(xa[1]));
        asm("v_cvt_pk_bf16_f32 %0, %1, %2" : "=v"(p1) : "v"(xa[2]), "v"(xa[3]));
        asm("v_cvt_pk_bf16_f32 %0, %1, %2" : "=v"(p2) : "v"(xb[0]), "v"(xb[1]));
        asm("v_cvt_pk_bf16_f32 %0, %1, %2" : "=v"(p3) : "v"(xb[2]), "v"(xb[3]));
        asm("v_cvt_pk_bf16_f32 %0, %1, %2" : "=v"(p4) : "v"(xc[0]), "v"(xc[1]));
        asm("v_cvt_pk_bf16_f32 %0, %1, %2" : "=v"(p5) : "v"(xc[2]), "v"(xc[3]));
        asm("v_cvt_pk_bf16_f32 %0, %1, %2" : "=v"(p6) : "v"(xd[0]), "v"(xd[1]));
        asm("v_cvt_pk_bf16_f32 %0, %1, %2" : "=v"(p7) : "v"(xd[2]), "v"(xd[3]));
        xf0 = __builtin_bit_cast(bf16x8, (u32x4){p0, p1, p2, p3});
        xf1 = __builtin_bit_cast(bf16x8, (u32x4){p4, p5, p6, p7});
    }

    __syncthreads();

    for (int t = 0; t < T_SZ; ++t) {
        // ---- x_{t+1} prefetch (4 vm loads; oldest in vmcnt order) ----
        {
            const float* xp = xbase + (size_t)((t + 1 < T_SZ) ? t + 1 : t) * I_SZ;
            asm volatile("global_load_dwordx4 %0, %1, off" : "=v"(xa) : "v"(xp) : "memory");
            asm volatile("global_load_dwordx4 %0, %1, off" : "=v"(xb) : "v"(xp + 4) : "memory");
            asm volatile("global_load_dwordx4 %0, %1, off" : "=v"(xc) : "v"(xp + 32) : "memory");
            asm volatile("global_load_dwordx4 %0, %1, off" : "=v"(xd) : "v"(xp + 36) : "memory");
        }
        // ---- prime 3 chunks (15 vm load-instrs, no VGPR dests) ----
        ISSUE(0); ISSUE(1); ISSUE(2);

        // ---- read h fragments (single buffer), then raw barrier ----
        bf16x8 ah[8];
        #pragma unroll
        for (int kf = 0; kf < 8; ++kf)
            ah[kf] = *(const bf16x8*)(&h_lds[n * HST + kf * 32 + hg * 8]);
        asm volatile("s_waitcnt lgkmcnt(0)" ::: "memory");
        __builtin_amdgcn_sched_barrier(0);
        __builtin_amdgcn_s_barrier();          // all h reads done; no vm drain

        f32x4 acc0 = {0.f, 0.f, 0.f, 0.f};
        f32x4 acc1 = {0.f, 0.f, 0.f, 0.f};
        f32x4 acc2 = {0.f, 0.f, 0.f, 0.f};
        f32x4 acc3 = {0.f, 0.f, 0.f, 0.f};
        TILE10(acc0, wr0);                     // resident: latency cover
        TILE10(acc1, wr1);

        CHUNK("10", 0, acc2, 0, ISSUE(3));     // k=0  (x + chunk0 retired)
        CHUNK("10", 1, acc2, 1, ISSUE(4));     // k=1
        CHUNK("10", 2, acc3, 0, ISSUE(5));     // k=2
        CHUNK("10", 0, acc3, 1, ISSUE(6));     // k=3

        EW(acc0, acc1, acc2, acc3, c0, bI0, bF0, bG0, bO0, 0);

        f32x4 acc4 = {0.f, 0.f, 0.f, 0.f};
        f32x4 acc5 = {0.f, 0.f, 0.f, 0.f};
        f32x4 acc6 = {0.f, 0.f, 0.f, 0.f};
        f32x4 acc7 = {0.f, 0.f, 0.f, 0.f};
        CHUNK("10", 1, acc4, 0, ISSUE(7));     // k=4
        CHUNK("10", 2, acc4, 1, ISSUE(8));     // k=5
        CHUNK("10", 0, acc5, 0, ISSUE(9));     // k=6
        CHUNK("10", 1, acc5, 1, ISSUE(10));    // k=7
        CHUNK("10", 2, acc6, 0, ISSUE(11));    // k=8
        CHUNK("10", 0, acc6, 1, (void)0);      // k=9
        CHUNK("5",  1, acc7, 0, (void)0);      // k=10
        CHUNK("0",  2, acc7, 1, (void)0);      // k=11 (x also drained)

        EW(acc4, acc5, acc6, acc7, c1, bI1, bF1, bG1, bO1, 1);

        // ---- convert x for next step (loads drained at k=11) ----
        {
            unsigned p0, p1, p2, p3, p4, p5, p6, p7;
            asm("v_cvt_pk_bf16_f32 %0, %1, %2" : "=v"(p0) : "v"(xa[0]), "v"(xa[1]));
            asm("v_cvt_pk_bf16_f32 %0, %1, %2" : "=v"(p1) : "v"(xa[2]), "v"(xa[3]));
            asm("v_cvt_pk_bf16_f32 %0, %1, %2" : "=v"(p2) : "v"(xb[0]), "v"(xb[1]));
            asm("v_cvt_pk_bf16_f32 %0, %1, %2" : "=v"(p3) : "v"(xb[2]), "v"(xb[3]));
            asm("v_cvt_pk_bf16_f32 %0, %1, %2" : "=v"(p4) : "v"(xc[0]), "v"(xc[1]));
            asm("v_cvt_pk_bf16_f32 %0, %1, %2" : "=v"(p5) : "v"(xc[2]), "v"(xc[3]));
            asm("v_cvt_pk_bf16_f32 %0, %1, %2" : "=v"(p6) : "v"(xd[0]), "v"(xd[1]));
            asm("v_cvt_pk_bf16_f32 %0, %1, %2" : "=v"(p7) : "v"(xd[2]), "v"(xd[3]));
            xf0 = __builtin_bit_cast(bf16x8, (u32x4){p0, p1, p2, p3});
            xf1 = __builtin_bit_cast(bf16x8, (u32x4){p4, p5, p6, p7});
        }

        // ---- h writes drained, then raw barrier (no vm drain) ----
        asm volatile("s_waitcnt lgkmcnt(0)" ::: "memory");
        __builtin_amdgcn_sched_barrier(0);
        __builtin_amdgcn_s_barrier();
    }

    // ---- heads (h_T in h_lds; loop-end barrier synced it) ----
    if (tid < 16 * 8) {
        int r = tid >> 3, cc = tid & 7;
        const float* wrow;
        float bb;
        if (cc == 0)      { wrow = W_dir;                 bb = b_dir[0]; }
        else if (cc <= 5) { wrow = W_q + (cc - 1) * H_SZ; bb = b_q[cc - 1]; }
        else if (cc == 6) { wrow = W_rr;                  bb = b_rr[0]; }
        else              { wrow = W_sl;                  bb = b_sl[0]; }
        float s = bb;
        for (int k = 0; k < H_SZ; ++k)
            s += bf2f(h_lds[r * HST + k]) * wrow[k];
        float v = (cc == 0) ? tanhfast(s) : (cc == 7) ? sigm(s) : s;
        out[(b0 + r) * 8 + cc] = v;
    }
}

extern "C" void kernel_launch(void* const* d_in, const int* in_sizes, int n_in,
                              void* d_out, int out_size, void* d_ws, size_t ws_size,
                              hipStream_t stream) {
    const float* x     = (const float*)d_in[0];
    const float* W_ih  = (const float*)d_in[1];
    const float* W_hh  = (const float*)d_in[2];
    const float* b_ih  = (const float*)d_in[3];
    const float* b_hh  = (const float*)d_in[4];
    const float* W_dir = (const float*)d_in[5];
    const float* b_dir = (const float*)d_in[6];
    const float* W_q   = (const float*)d_in[7];
    const float* b_q   = (const float*)d_in[8];
    const float* W_rr  = (const float*)d_in[9];
    const float* b_rr  = (const float*)d_in[10];
    const float* W_sl  = (const float*)d_in[11];
    const float* b_sl  = (const float*)d_in[12];

    unsigned short* Wt = (unsigned short*)d_ws;
    float* bias        = (float*)((char*)d_ws + WS_BIAS_OFF);
    float* outp        = (float*)d_out;

    prep_kernel<<<164, 256, 0, stream>>>(W_ih, W_hh, b_ih, b_hh, Wt, bias);
    lstm_kernel<<<NBLK, NTHREADS, 0, stream>>>(x, Wt, bias,
                                               W_dir, b_dir, W_q, b_q,
                                               W_rr, b_rr, W_sl, b_sl, outp);
}